// Round 5
// baseline (1919.243 us; speedup 1.0000x reference)
//
#include <hip/hip_runtime.h>
#include <hip/hip_bf16.h>

// ---------------------------------------------------------------------------
// Fused 3-layer GRU (Keras reset_after) + dense + softmax for MI355X (gfx950).
// B=131072, T=3, F=223, units (128,64,32), 17 classes.
// R3: spill elimination. Gate-merged accumulators (z/r accumulate x@k AND h@rk
// into one f32x4), biases folded into accumulator init (staged in LDS),
// launch_bounds(256,3) -> ~170 VGPR budget, 3 blocks/CU.
// ---------------------------------------------------------------------------

typedef _Float16 half8 __attribute__((ext_vector_type(8)));
typedef float f32x4 __attribute__((ext_vector_type(4)));

#define MFMA16(a, b, c) __builtin_amdgcn_mfma_f32_16x16x32_f16((a), (b), (c), 0, 0, 0)

// d_ws layout (f16 elements):
//   k1T  [384][224] @ 0        (K padded 223->224, pad = 0)
//   rk1T [384][128] @ 86016
//   k2T  [192][128] @ 135168
//   rk2T [192][ 64] @ 159744
//   k3T  [ 96][ 64] @ 172032
//   rk3T [ 96][ 32] @ 178176   total 181248 elems = 362496 B
#define OFF_RK1 86016
#define OFF_K2  135168
#define OFF_RK2 159744
#define OFF_K3  172032
#define OFF_RK3 178176
#define WS_ELEMS 181248

__global__ void prep_weights(const float* __restrict__ k1, const float* __restrict__ rk1,
                             const float* __restrict__ k2, const float* __restrict__ rk2,
                             const float* __restrict__ k3, const float* __restrict__ rk3,
                             _Float16* __restrict__ o) {
    int i = blockIdx.x * 256 + threadIdx.x;
    if (i < 86016) {                    // k1T [384][224] <- k1 [223][384]
        int n = i / 224, k = i - n * 224;
        o[i] = (_Float16)(k < 223 ? k1[k * 384 + n] : 0.0f);
        return;
    }
    i -= 86016;
    if (i < 49152) {                    // rk1T [384][128] <- rk1 [128][384]
        int n = i / 128, k = i - n * 128;
        o[OFF_RK1 + i] = (_Float16)rk1[k * 384 + n];
        return;
    }
    i -= 49152;
    if (i < 24576) {                    // k2T [192][128] <- k2 [128][192]
        int n = i / 128, k = i - n * 128;
        o[OFF_K2 + i] = (_Float16)k2[k * 192 + n];
        return;
    }
    i -= 24576;
    if (i < 12288) {                    // rk2T [192][64] <- rk2 [64][192]
        int n = i / 64, k = i - n * 64;
        o[OFF_RK2 + i] = (_Float16)rk2[k * 192 + n];
        return;
    }
    i -= 12288;
    if (i < 6144) {                     // k3T [96][64] <- k3 [64][96]
        int n = i / 64, k = i - n * 64;
        o[OFF_K3 + i] = (_Float16)k3[k * 96 + n];
        return;
    }
    i -= 6144;
    if (i < 3072) {                     // rk3T [96][32] <- rk3 [32][96]
        int n = i / 32, k = i - n * 32;
        o[OFF_RK3 + i] = (_Float16)rk3[k * 96 + n];
        return;
    }
}

__device__ __forceinline__ float sigmoidf_(float v) { return 1.0f / (1.0f + __expf(-v)); }
__device__ __forceinline__ float tanhf_(float v) { return 1.0f - 2.0f / (1.0f + __expf(2.0f * v)); }

// LDS strides (f16 elems). All give odd 16B-chunk row strides -> minimal
// (2-way, ~free) bank aliasing on ds_read_b128.
#define XS_STR  232   // x tile: 32 x 232 (cols 0..222 valid, 223 zero-padded)
#define H1_STR  136
#define H2_STR  72
#define H3_STR  40
// bias LDS layout (f32, after the f16 area):
//   [0,256)   b1 z+r sums     [256,384) b1 h input   [384,512) b1 h recur
//   [512,640) b2 z+r sums     [640,704) b2 h input   [704,768) b2 h recur
//   [768,832) b3 z+r sums     [832,864) b3 h input   [864,896) b3 h recur

__global__ __launch_bounds__(256, 3) void gru_fused(
    const float* __restrict__ x, const _Float16* __restrict__ wts,
    const float* __restrict__ b1, const float* __restrict__ b2, const float* __restrict__ b3,
    const float* __restrict__ Wd, const float* __restrict__ bd,
    float* __restrict__ out) {
    __shared__ __align__(16) _Float16 smem[32 * (XS_STR + H1_STR + H2_STR + H3_STR) + 896 * 2];
    _Float16* xs  = smem;
    _Float16* hs1 = smem + 32 * XS_STR;
    _Float16* hs2 = hs1 + 32 * H1_STR;
    _Float16* hs3 = hs2 + 32 * H2_STR;
    float*    bsm = (float*)(hs3 + 32 * H3_STR);

    const int tid  = threadIdx.x;
    const int lane = tid & 63;
    const int w    = tid >> 6;          // wave 0..3
    const int ln15 = lane & 15;
    const int kg8  = (lane >> 4) * 8;   // k-offset of this lane's 8-elem block
    const int rowg = (lane >> 4) * 4;   // C/D row group
    const int b0   = blockIdx.x * 32;

    const _Float16* k1T  = wts;
    const _Float16* rk1T = wts + OFF_RK1;
    const _Float16* k2T  = wts + OFF_K2;
    const _Float16* rk2T = wts + OFF_RK2;
    const _Float16* k3T  = wts + OFF_K3;
    const _Float16* rk3T = wts + OFF_RK3;

    // zero h LDS (h1,h2,h3 contiguous): 32*(136+72+40) = 7936 halves = 3968 u32
    for (int i = tid; i < 3968; i += 256) ((unsigned*)hs1)[i] = 0u;
    // stage biases (z/r pre-summed; h-gate input/recurrent kept separate)
    for (int i = tid; i < 896; i += 256) {
        float v;
        if      (i < 256) v = b1[i] + b1[384 + i];
        else if (i < 384) v = b1[i];            // i=256+j -> b1[256+j]
        else if (i < 512) v = b1[256 + i];      // i=384+j -> b1[640+j]
        else if (i < 640) { int u = i - 512; v = b2[u] + b2[192 + u]; }
        else if (i < 704) { int j = i - 640; v = b2[128 + j]; }
        else if (i < 768) { int j = i - 704; v = b2[320 + j]; }
        else if (i < 832) { int u = i - 768; v = b3[u] + b3[96 + u]; }
        else if (i < 864) { int j = i - 832; v = b3[64 + j]; }
        else              { int j = i - 864; v = b3[160 + j]; }
        bsm[i] = v;
    }

    const int u1b = w * 32;             // L1: wave owns units [32w, 32w+32)
    const int u2  = w * 16 + ln15;      // L2: wave owns units [16w, 16w+16)
    const int u3  = (w & 1) * 16 + ln15;// L3: unit half per wave parity
    const int mi3 = w >> 1;             // L3: row half per wave pair

    float h1r[2][2][4]; // [ci][mi][r]
    float h2r[2][4];    // [mi][r]
    float h3r[4];
#pragma unroll
    for (int ci = 0; ci < 2; ++ci)
#pragma unroll
        for (int mi = 0; mi < 2; ++mi)
#pragma unroll
            for (int r = 0; r < 4; ++r) h1r[ci][mi][r] = 0.0f;
#pragma unroll
    for (int mi = 0; mi < 2; ++mi)
#pragma unroll
        for (int r = 0; r < 4; ++r) h2r[mi][r] = 0.0f;
#pragma unroll
    for (int r = 0; r < 4; ++r) h3r[r] = 0.0f;

    __syncthreads();

    for (int t = 0; t < 3; ++t) {
        // ---- stage x_t tile -> LDS f16 ----
        for (int p = tid; p < 32 * 112; p += 256) {
            int m = p / 112, q = p - m * 112;
            const float* xr = x + ((size_t)(b0 + m) * 3 + t) * 223;
            float v0 = xr[2 * q];
            float v1 = (2 * q + 1 < 223) ? xr[2 * q + 1] : 0.0f;
            union { _Float16 h[2]; unsigned u; } pk;
            pk.h[0] = (_Float16)v0;
            pk.h[1] = (_Float16)v1;
            *(unsigned*)&xs[m * XS_STR + 2 * q] = pk.u;
        }
        __syncthreads();

        // ================= Layer 1 (K=224 in, K=128 rec, N=384) =================
        // Gate-merged: aZ/aR accumulate BOTH x@k and h@rk (+ summed bias init).
        f32x4 aZ[2][2], aR[2][2], aXH[2][2], aIH[2][2]; // [ci][mi]
#pragma unroll
        for (int ci = 0; ci < 2; ++ci) {
            int u = u1b + ci * 16 + ln15;
            float bz = bsm[u], br_ = bsm[128 + u], bxh = bsm[256 + u], bih = bsm[384 + u];
#pragma unroll
            for (int mi = 0; mi < 2; ++mi) {
                aZ[ci][mi]  = (f32x4){bz, bz, bz, bz};
                aR[ci][mi]  = (f32x4){br_, br_, br_, br_};
                aXH[ci][mi] = (f32x4){bxh, bxh, bxh, bxh};
                aIH[ci][mi] = (f32x4){bih, bih, bih, bih};
            }
        }
#pragma unroll
        for (int ks = 0; ks < 7; ++ks) {
            int k0 = ks * 32;
            half8 a0 = *(const half8*)(xs + ln15 * XS_STR + k0 + kg8);
            half8 a1 = *(const half8*)(xs + (16 + ln15) * XS_STR + k0 + kg8);
#pragma unroll
            for (int ci = 0; ci < 2; ++ci) {
                const _Float16* col = k1T + (size_t)(u1b + ci * 16 + ln15) * 224 + k0 + kg8;
                half8 bz = *(const half8*)(col);
                half8 br = *(const half8*)(col + (size_t)128 * 224);
                half8 bh = *(const half8*)(col + (size_t)256 * 224);
                aZ[ci][0]  = MFMA16(a0, bz, aZ[ci][0]);  aZ[ci][1]  = MFMA16(a1, bz, aZ[ci][1]);
                aR[ci][0]  = MFMA16(a0, br, aR[ci][0]);  aR[ci][1]  = MFMA16(a1, br, aR[ci][1]);
                aXH[ci][0] = MFMA16(a0, bh, aXH[ci][0]); aXH[ci][1] = MFMA16(a1, bh, aXH[ci][1]);
            }
        }
#pragma unroll
        for (int ks = 0; ks < 4; ++ks) {
            int k0 = ks * 32;
            half8 a0 = *(const half8*)(hs1 + ln15 * H1_STR + k0 + kg8);
            half8 a1 = *(const half8*)(hs1 + (16 + ln15) * H1_STR + k0 + kg8);
#pragma unroll
            for (int ci = 0; ci < 2; ++ci) {
                const _Float16* col = rk1T + (size_t)(u1b + ci * 16 + ln15) * 128 + k0 + kg8;
                half8 bz = *(const half8*)(col);
                half8 br = *(const half8*)(col + (size_t)128 * 128);
                half8 bh = *(const half8*)(col + (size_t)256 * 128);
                aZ[ci][0]  = MFMA16(a0, bz, aZ[ci][0]);  aZ[ci][1]  = MFMA16(a1, bz, aZ[ci][1]);
                aR[ci][0]  = MFMA16(a0, br, aR[ci][0]);  aR[ci][1]  = MFMA16(a1, br, aR[ci][1]);
                aIH[ci][0] = MFMA16(a0, bh, aIH[ci][0]); aIH[ci][1] = MFMA16(a1, bh, aIH[ci][1]);
            }
        }
        __syncthreads(); // all waves done reading hs1 (t-1) and xs
#pragma unroll
        for (int ci = 0; ci < 2; ++ci)
#pragma unroll
            for (int mi = 0; mi < 2; ++mi)
#pragma unroll
                for (int r = 0; r < 4; ++r) {
                    float zg = sigmoidf_(aZ[ci][mi][r]);
                    float rg = sigmoidf_(aR[ci][mi][r]);
                    float hh = tanhf_(aXH[ci][mi][r] + rg * aIH[ci][mi][r]);
                    float hn = zg * h1r[ci][mi][r] + (1.0f - zg) * hh;
                    h1r[ci][mi][r] = hn;
                    hs1[(mi * 16 + rowg + r) * H1_STR + u1b + ci * 16 + ln15] = (_Float16)hn;
                }
        __syncthreads(); // hs1 = h1_t ready

        // ================= Layer 2 (K=128 in, K=64 rec, N=192) =================
        f32x4 aZ2[2], aR2[2], aXH2[2], aIH2[2]; // [mi]
        {
            float bz = bsm[512 + u2], br_ = bsm[576 + u2], bxh = bsm[640 + u2], bih = bsm[704 + u2];
#pragma unroll
            for (int mi = 0; mi < 2; ++mi) {
                aZ2[mi]  = (f32x4){bz, bz, bz, bz};
                aR2[mi]  = (f32x4){br_, br_, br_, br_};
                aXH2[mi] = (f32x4){bxh, bxh, bxh, bxh};
                aIH2[mi] = (f32x4){bih, bih, bih, bih};
            }
        }
#pragma unroll
        for (int ks = 0; ks < 4; ++ks) {
            int k0 = ks * 32;
            half8 a0 = *(const half8*)(hs1 + ln15 * H1_STR + k0 + kg8);
            half8 a1 = *(const half8*)(hs1 + (16 + ln15) * H1_STR + k0 + kg8);
            const _Float16* col = k2T + (size_t)u2 * 128 + k0 + kg8;
            half8 bz = *(const half8*)(col);
            half8 br = *(const half8*)(col + (size_t)64 * 128);
            half8 bh = *(const half8*)(col + (size_t)128 * 128);
            aZ2[0]  = MFMA16(a0, bz, aZ2[0]);  aZ2[1]  = MFMA16(a1, bz, aZ2[1]);
            aR2[0]  = MFMA16(a0, br, aR2[0]);  aR2[1]  = MFMA16(a1, br, aR2[1]);
            aXH2[0] = MFMA16(a0, bh, aXH2[0]); aXH2[1] = MFMA16(a1, bh, aXH2[1]);
        }
#pragma unroll
        for (int ks = 0; ks < 2; ++ks) {
            int k0 = ks * 32;
            half8 a0 = *(const half8*)(hs2 + ln15 * H2_STR + k0 + kg8);
            half8 a1 = *(const half8*)(hs2 + (16 + ln15) * H2_STR + k0 + kg8);
            const _Float16* col = rk2T + (size_t)u2 * 64 + k0 + kg8;
            half8 bz = *(const half8*)(col);
            half8 br = *(const half8*)(col + (size_t)64 * 64);
            half8 bh = *(const half8*)(col + (size_t)128 * 64);
            aZ2[0]  = MFMA16(a0, bz, aZ2[0]);  aZ2[1]  = MFMA16(a1, bz, aZ2[1]);
            aR2[0]  = MFMA16(a0, br, aR2[0]);  aR2[1]  = MFMA16(a1, br, aR2[1]);
            aIH2[0] = MFMA16(a0, bh, aIH2[0]); aIH2[1] = MFMA16(a1, bh, aIH2[1]);
        }
        __syncthreads(); // done reading hs1(t), hs2(t-1)
#pragma unroll
        for (int mi = 0; mi < 2; ++mi)
#pragma unroll
            for (int r = 0; r < 4; ++r) {
                float zg = sigmoidf_(aZ2[mi][r]);
                float rg = sigmoidf_(aR2[mi][r]);
                float hh = tanhf_(aXH2[mi][r] + rg * aIH2[mi][r]);
                float hn = zg * h2r[mi][r] + (1.0f - zg) * hh;
                h2r[mi][r] = hn;
                hs2[(mi * 16 + rowg + r) * H2_STR + w * 16 + ln15] = (_Float16)hn;
            }
        __syncthreads(); // hs2 = h2_t ready

        // ================= Layer 3 (K=64 in, K=32 rec, N=96) =================
        // wave w: rows [16*(w>>1), +16), units [16*(w&1), +16)
        f32x4 aZ3, aR3, aXH3, aIH3;
        {
            float bz = bsm[768 + u3], br_ = bsm[800 + u3], bxh = bsm[832 + u3], bih = bsm[864 + u3];
            aZ3  = (f32x4){bz, bz, bz, bz};
            aR3  = (f32x4){br_, br_, br_, br_};
            aXH3 = (f32x4){bxh, bxh, bxh, bxh};
            aIH3 = (f32x4){bih, bih, bih, bih};
        }
#pragma unroll
        for (int ks = 0; ks < 2; ++ks) {
            int k0 = ks * 32;
            half8 a = *(const half8*)(hs2 + (mi3 * 16 + ln15) * H2_STR + k0 + kg8);
            const _Float16* col = k3T + (size_t)u3 * 64 + k0 + kg8;
            half8 bz = *(const half8*)(col);
            half8 br = *(const half8*)(col + (size_t)32 * 64);
            half8 bh = *(const half8*)(col + (size_t)64 * 64);
            aZ3  = MFMA16(a, bz, aZ3);
            aR3  = MFMA16(a, br, aR3);
            aXH3 = MFMA16(a, bh, aXH3);
        }
        {
            half8 a = *(const half8*)(hs3 + (mi3 * 16 + ln15) * H3_STR + kg8);
            const _Float16* col = rk3T + (size_t)u3 * 32 + kg8;
            half8 bz = *(const half8*)(col);
            half8 br = *(const half8*)(col + (size_t)32 * 32);
            half8 bh = *(const half8*)(col + (size_t)64 * 32);
            aZ3  = MFMA16(a, bz, aZ3);
            aR3  = MFMA16(a, br, aR3);
            aIH3 = MFMA16(a, bh, aIH3);
        }
        __syncthreads(); // done reading hs2(t), hs3(t-1)
#pragma unroll
        for (int r = 0; r < 4; ++r) {
            float zg = sigmoidf_(aZ3[r]);
            float rg = sigmoidf_(aR3[r]);
            float hh = tanhf_(aXH3[r] + rg * aIH3[r]);
            float hn = zg * h3r[r] + (1.0f - zg) * hh;
            h3r[r] = hn;
            hs3[(mi3 * 16 + rowg + r) * H3_STR + (w & 1) * 16 + ln15] = (_Float16)hn;
        }
        __syncthreads(); // hs3 = h3_t ready
    } // t

    // ================= Dense (32 -> 17) + softmax =================
    float* lg = (float*)xs; // reuse x LDS: 32 rows x stride 20 floats
    for (int idx = tid; idx < 32 * 17; idx += 256) {
        int m = idx / 17, c = idx - m * 17;
        float acc = bd[c];
#pragma unroll
        for (int k = 0; k < 32; ++k) acc += (float)hs3[m * H3_STR + k] * Wd[k * 17 + c];
        lg[m * 20 + c] = acc;
    }
    __syncthreads();
    if (tid < 32) {
        int m = tid;
        float mx = -1e30f;
#pragma unroll
        for (int c = 0; c < 17; ++c) mx = fmaxf(mx, lg[m * 20 + c]);
        float sum = 0.0f;
#pragma unroll
        for (int c = 0; c < 17; ++c) { float e = __expf(lg[m * 20 + c] - mx); lg[m * 20 + c] = e; sum += e; }
        float inv = 1.0f / sum;
        float* op = out + (size_t)(b0 + m) * 17;
#pragma unroll
        for (int c = 0; c < 17; ++c) op[c] = lg[m * 20 + c] * inv;
    }
}

extern "C" void kernel_launch(void* const* d_in, const int* in_sizes, int n_in,
                              void* d_out, int out_size, void* d_ws, size_t ws_size,
                              hipStream_t stream) {
    const float* x   = (const float*)d_in[0];
    const float* k1  = (const float*)d_in[1];
    const float* rk1 = (const float*)d_in[2];
    const float* b1  = (const float*)d_in[3];
    const float* k2  = (const float*)d_in[4];
    const float* rk2 = (const float*)d_in[5];
    const float* b2  = (const float*)d_in[6];
    const float* k3  = (const float*)d_in[7];
    const float* rk3 = (const float*)d_in[8];
    const float* b3  = (const float*)d_in[9];
    const float* Wd  = (const float*)d_in[10];
    const float* bd  = (const float*)d_in[11];
    float* out = (float*)d_out;
    _Float16* wts = (_Float16*)d_ws;

    prep_weights<<<dim3(WS_ELEMS / 256), dim3(256), 0, stream>>>(k1, rk1, k2, rk2, k3, rk3, wts);
    gru_fused<<<dim3(4096), dim3(256), 0, stream>>>(x, wts, b1, b2, b3, Wd, bd, out);
}